// Round 1
// baseline (5991.597 us; speedup 1.0000x reference)
//
#include <hip/hip_runtime.h>

// Problem constants (from reference)
#define N_NODES 100000
#define N_EDGES 3200000
#define IN_CH   256
#define OUT_CH  128

// -------------------------------------------------------------------------
// Kernel 1: xw = x @ W   (fp32 vector GEMM, register-blocked)
// block = 256 threads: 8 rows x 32 channel-groups (4 ch each).
// W reads are shared across the 8 row-groups -> L1 broadcast hits.
// -------------------------------------------------------------------------
__global__ __launch_bounds__(256) void gemm_kernel(const float* __restrict__ x,
                                                   const float* __restrict__ w,
                                                   float* __restrict__ xw) {
    int tid  = threadIdx.x;
    int cg   = tid & 31;        // channel group -> channels cg*4 .. cg*4+3
    int rowg = tid >> 5;        // 0..7
    int r    = blockIdx.x * 8 + rowg;
    if (r >= N_NODES) return;

    const float4* x4 = (const float4*)(x + (long long)r * IN_CH);
    int c = cg * 4;
    float4 acc = make_float4(0.f, 0.f, 0.f, 0.f);

    for (int k = 0; k < IN_CH; k += 4) {
        float4 xv = x4[k >> 2];
        float4 w0 = *(const float4*)&w[(k + 0) * OUT_CH + c];
        float4 w1 = *(const float4*)&w[(k + 1) * OUT_CH + c];
        float4 w2 = *(const float4*)&w[(k + 2) * OUT_CH + c];
        float4 w3 = *(const float4*)&w[(k + 3) * OUT_CH + c];
        acc.x += xv.x * w0.x + xv.y * w1.x + xv.z * w2.x + xv.w * w3.x;
        acc.y += xv.x * w0.y + xv.y * w1.y + xv.z * w2.y + xv.w * w3.y;
        acc.z += xv.x * w0.z + xv.y * w1.z + xv.z * w2.z + xv.w * w3.z;
        acc.w += xv.x * w0.w + xv.y * w1.w + xv.z * w2.w + xv.w * w3.w;
    }
    *(float4*)&xw[(long long)r * OUT_CH + c] = acc;
}

// -------------------------------------------------------------------------
// Kernel 2: out[n][c] = bias[c]  (d_out is poisoned 0xAA before every call)
// One float4 per thread; 12.8M floats -> 3.2M threads.
// -------------------------------------------------------------------------
__global__ __launch_bounds__(256) void init_kernel(const float* __restrict__ bias,
                                                   float* __restrict__ out) {
    int idx = blockIdx.x * blockDim.x + threadIdx.x;   // float4 index
    float4 b = *(const float4*)&bias[(idx & 31) * 4];  // 128 ch = 32 float4s
    ((float4*)out)[idx] = b;
}

// -------------------------------------------------------------------------
// Kernel 3: edge scatter. 32 lanes per edge (float4 of channels each),
// 2 edges per wave. Gather xw[dst] (512 B coalesced), scale by edge_vals,
// fire-and-forget global_atomic_add_f32 into out[src].
// -------------------------------------------------------------------------
__global__ __launch_bounds__(256) void scatter_kernel(const int* __restrict__ src,
                                                      const int* __restrict__ dst,
                                                      const float* __restrict__ val,
                                                      const float* __restrict__ xw,
                                                      float* out) {
    int gtid   = blockIdx.x * blockDim.x + threadIdx.x;
    int lane   = threadIdx.x & 63;
    int cg     = lane & 31;           // channel group
    int half   = lane >> 5;           // which of the 2 edges this wave handles
    int waveId = gtid >> 6;
    int nWaves = (gridDim.x * blockDim.x) >> 6;

    for (int e = waveId * 2 + half; e < N_EDGES; e += nWaves * 2) {
        int   s = src[e];
        int   d = dst[e];
        float v = val[e];
        float4 m = *(const float4*)&xw[(long long)d * OUT_CH + cg * 4];
        float* o = out + (long long)s * OUT_CH + cg * 4;
        atomicAdd(o + 0, m.x * v);
        atomicAdd(o + 1, m.y * v);
        atomicAdd(o + 2, m.z * v);
        atomicAdd(o + 3, m.w * v);
    }
}

extern "C" void kernel_launch(void* const* d_in, const int* in_sizes, int n_in,
                              void* d_out, int out_size, void* d_ws, size_t ws_size,
                              hipStream_t stream) {
    const float* x     = (const float*)d_in[0];
    const int*   esrc  = (const int*)d_in[1];
    const int*   edst  = (const int*)d_in[2];
    const float* evals = (const float*)d_in[3];
    const float* w     = (const float*)d_in[4];
    const float* bias  = (const float*)d_in[5];
    float* out = (float*)d_out;
    float* xw  = (float*)d_ws;   // needs N_NODES*OUT_CH*4 = 51.2 MB of scratch

    // xw = x @ W
    gemm_kernel<<<N_NODES / 8, 256, 0, stream>>>(x, w, xw);
    // out = bias (broadcast)
    init_kernel<<<(N_NODES * OUT_CH / 4) / 256, 256, 0, stream>>>(bias, out);
    // out[src] += xw[dst] * val  (atomic scatter)
    scatter_kernel<<<4096, 256, 0, stream>>>(esrc, edst, evals, xw, out);
}

// Round 2
// 975.488 us; speedup vs baseline: 6.1422x; 6.1422x over previous
//
#include <hip/hip_runtime.h>

// Problem constants (from reference)
#define N_NODES 100000
#define N_EDGES 3200000
#define IN_CH   256
#define OUT_CH  128

// ---------------------------------------------------------------------------
// Workspace layout (bytes):
//   xw      [N_NODES*OUT_CH] f32   : 51,200,000
//   deg     [N_NODES]        i32   :    400,000
//   row_ptr [N_NODES+1+pad]  i32   :    400,016
//   cursor  [N_NODES]        i32   :    400,000
//   packed  [N_EDGES]        int2  : 25,600,000   {dst, bitcast(val)}
// total = 78,000,016
// ---------------------------------------------------------------------------
#define OFF_XW      0
#define OFF_DEG     51200000
#define OFF_ROWPTR  51600000
#define OFF_CURSOR  52000016
#define OFF_PACKED  52400016
#define WS_REQUIRED 78000016ULL

// ---------------------------------------------------------------------------
// Kernel 1: xw = x @ W. 4x4 register blocking: 256 thr = 32 ch-groups x 8
// row-groups, each thread computes 4 rows x 4 channels. Block covers 32 rows.
// ---------------------------------------------------------------------------
__global__ __launch_bounds__(256) void gemm_kernel(const float* __restrict__ x,
                                                   const float* __restrict__ w,
                                                   float* __restrict__ xw) {
    int tid  = threadIdx.x;
    int cg   = tid & 31;          // channel group: channels cg*4..cg*4+3
    int rowg = tid >> 5;          // 0..7
    int r0   = blockIdx.x * 32 + rowg * 4;

    const float4* w4 = (const float4*)w;     // w[k][c] -> w4[k*32 + cg]
    const float*  xr0 = x + (long long)r0 * IN_CH;

    float4 a0 = make_float4(0.f, 0.f, 0.f, 0.f);
    float4 a1 = a0, a2 = a0, a3 = a0;

    for (int k = 0; k < IN_CH; k += 4) {
        float4 w0 = w4[(k + 0) * 32 + cg];
        float4 w1 = w4[(k + 1) * 32 + cg];
        float4 w2 = w4[(k + 2) * 32 + cg];
        float4 w3 = w4[(k + 3) * 32 + cg];
        float4 x0 = *(const float4*)&xr0[0 * IN_CH + k];
        float4 x1 = *(const float4*)&xr0[1 * IN_CH + k];
        float4 x2 = *(const float4*)&xr0[2 * IN_CH + k];
        float4 x3 = *(const float4*)&xr0[3 * IN_CH + k];

        a0.x += x0.x*w0.x + x0.y*w1.x + x0.z*w2.x + x0.w*w3.x;
        a0.y += x0.x*w0.y + x0.y*w1.y + x0.z*w2.y + x0.w*w3.y;
        a0.z += x0.x*w0.z + x0.y*w1.z + x0.z*w2.z + x0.w*w3.z;
        a0.w += x0.x*w0.w + x0.y*w1.w + x0.z*w2.w + x0.w*w3.w;

        a1.x += x1.x*w0.x + x1.y*w1.x + x1.z*w2.x + x1.w*w3.x;
        a1.y += x1.x*w0.y + x1.y*w1.y + x1.z*w2.y + x1.w*w3.y;
        a1.z += x1.x*w0.z + x1.y*w1.z + x1.z*w2.z + x1.w*w3.z;
        a1.w += x1.x*w0.w + x1.y*w1.w + x1.z*w2.w + x1.w*w3.w;

        a2.x += x2.x*w0.x + x2.y*w1.x + x2.z*w2.x + x2.w*w3.x;
        a2.y += x2.x*w0.y + x2.y*w1.y + x2.z*w2.y + x2.w*w3.y;
        a2.z += x2.x*w0.z + x2.y*w1.z + x2.z*w2.z + x2.w*w3.z;
        a2.w += x2.x*w0.w + x2.y*w1.w + x2.z*w2.w + x2.w*w3.w;

        a3.x += x3.x*w0.x + x3.y*w1.x + x3.z*w2.x + x3.w*w3.x;
        a3.y += x3.x*w0.y + x3.y*w1.y + x3.z*w2.y + x3.w*w3.y;
        a3.z += x3.x*w0.z + x3.y*w1.z + x3.z*w2.z + x3.w*w3.z;
        a3.w += x3.x*w0.w + x3.y*w1.w + x3.z*w2.w + x3.w*w3.w;
    }
    int c = cg * 4;
    *(float4*)&xw[(long long)(r0 + 0) * OUT_CH + c] = a0;
    *(float4*)&xw[(long long)(r0 + 1) * OUT_CH + c] = a1;
    *(float4*)&xw[(long long)(r0 + 2) * OUT_CH + c] = a2;
    *(float4*)&xw[(long long)(r0 + 3) * OUT_CH + c] = a3;
}

// ---------------------------------------------------------------------------
// CSR build: zero degrees -> histogram -> exclusive scan -> permute edges
// ---------------------------------------------------------------------------
__global__ __launch_bounds__(256) void zero_kernel(int* __restrict__ deg) {
    int i = (blockIdx.x * 256 + threadIdx.x) * 4;
    if (i < N_NODES) *(int4*)&deg[i] = make_int4(0, 0, 0, 0);
}

__global__ __launch_bounds__(256) void hist_kernel(const int* __restrict__ src,
                                                   int* __restrict__ deg) {
    int e0 = (blockIdx.x * 256 + threadIdx.x) * 4;
    int4 s = *(const int4*)&src[e0];
    atomicAdd(&deg[s.x], 1);
    atomicAdd(&deg[s.y], 1);
    atomicAdd(&deg[s.z], 1);
    atomicAdd(&deg[s.w], 1);
}

// Single-workgroup chunked scan: 1024 threads x 4 elems = 4096/iter, 25 iters.
__global__ __launch_bounds__(1024) void scan_kernel(const int* __restrict__ deg,
                                                    int* __restrict__ row_ptr,
                                                    int* __restrict__ cursor) {
    __shared__ int wsum[16];
    int tid = threadIdx.x, lane = tid & 63, wid = tid >> 6;
    int carry = 0;
    for (int base = 0; base < N_NODES; base += 4096) {
        int i0 = base + tid * 4;
        int4 v = make_int4(0, 0, 0, 0);
        if (i0 < N_NODES) v = *(const int4*)&deg[i0];   // N_NODES % 4 == 0
        int sum4 = v.x + v.y + v.z + v.w;
        int s = sum4;
#pragma unroll
        for (int off = 1; off < 64; off <<= 1) {
            int t = __shfl_up(s, off, 64);
            if (lane >= off) s += t;
        }
        if (lane == 63) wsum[wid] = s;
        __syncthreads();
        if (wid == 0 && lane < 16) {
            int wv = wsum[lane];
#pragma unroll
            for (int off = 1; off < 16; off <<= 1) {
                int t = __shfl_up(wv, off, 64);
                if (lane >= off) wv += t;
            }
            wsum[lane] = wv;   // inclusive wave prefix
        }
        __syncthreads();
        int woff  = (wid == 0) ? 0 : wsum[wid - 1];
        int total = wsum[15];
        int excl  = carry + woff + (s - sum4);
        if (i0 < N_NODES) {
            int4 r = make_int4(excl, excl + v.x, excl + v.x + v.y,
                               excl + v.x + v.y + v.z);
            *(int4*)&row_ptr[i0] = r;
            *(int4*)&cursor[i0]  = r;
        }
        carry += total;
        __syncthreads();
    }
    if (tid == 0) row_ptr[N_NODES] = carry;
}

__global__ __launch_bounds__(256) void build_kernel(const int* __restrict__ src,
                                                    const int* __restrict__ dst,
                                                    const float* __restrict__ val,
                                                    int* __restrict__ cursor,
                                                    int2* __restrict__ packed) {
    int e0 = (blockIdx.x * 256 + threadIdx.x) * 4;
    int4   s = *(const int4*)&src[e0];
    int4   d = *(const int4*)&dst[e0];
    float4 v = *(const float4*)&val[e0];
    int p;
    p = atomicAdd(&cursor[s.x], 1); packed[p] = make_int2(d.x, __float_as_int(v.x));
    p = atomicAdd(&cursor[s.y], 1); packed[p] = make_int2(d.y, __float_as_int(v.y));
    p = atomicAdd(&cursor[s.z], 1); packed[p] = make_int2(d.z, __float_as_int(v.z));
    p = atomicAdd(&cursor[s.w], 1); packed[p] = make_int2(d.w, __float_as_int(v.w));
}

// ---------------------------------------------------------------------------
// Aggregate: one node per wave. 64 lanes x float2 = 128 channels. Register
// accumulation, bias fused, single output write — zero output atomics.
// ---------------------------------------------------------------------------
__global__ __launch_bounds__(256) void aggregate_kernel(const int* __restrict__ row_ptr,
                                                        const int2* __restrict__ packed,
                                                        const float* __restrict__ xw,
                                                        const float* __restrict__ bias,
                                                        float* __restrict__ out) {
    int node = blockIdx.x * 4 + (threadIdx.x >> 6);   // 25000 blocks x 4 waves
    int lane = threadIdx.x & 63;
    const float2* xw2 = (const float2*)xw;            // xw2[node*64 + lane]

    float2 acc = *(const float2*)&bias[lane * 2];
    int beg = row_ptr[node];
    int end = row_ptr[node + 1];

    int e = beg;
    for (; e + 4 <= end; e += 4) {
        int2 p0 = packed[e + 0];
        int2 p1 = packed[e + 1];
        int2 p2 = packed[e + 2];
        int2 p3 = packed[e + 3];
        float2 m0 = xw2[p0.x * 64 + lane];
        float2 m1 = xw2[p1.x * 64 + lane];
        float2 m2 = xw2[p2.x * 64 + lane];
        float2 m3 = xw2[p3.x * 64 + lane];
        float v0 = __int_as_float(p0.y), v1 = __int_as_float(p1.y);
        float v2 = __int_as_float(p2.y), v3 = __int_as_float(p3.y);
        acc.x += v0 * m0.x; acc.y += v0 * m0.y;
        acc.x += v1 * m1.x; acc.y += v1 * m1.y;
        acc.x += v2 * m2.x; acc.y += v2 * m2.y;
        acc.x += v3 * m3.x; acc.y += v3 * m3.y;
    }
    for (; e < end; ++e) {
        int2 p = packed[e];
        float2 m = xw2[p.x * 64 + lane];
        float v = __int_as_float(p.y);
        acc.x += v * m.x; acc.y += v * m.y;
    }
    *(float2*)&out[(long long)node * OUT_CH + lane * 2] = acc;
}

// ---------------------------------------------------------------------------
// Fallback path (ws too small): bias init + atomic scatter (R1 structure)
// ---------------------------------------------------------------------------
__global__ __launch_bounds__(256) void init_kernel(const float* __restrict__ bias,
                                                   float* __restrict__ out) {
    int idx = blockIdx.x * blockDim.x + threadIdx.x;
    float4 b = *(const float4*)&bias[(idx & 31) * 4];
    ((float4*)out)[idx] = b;
}

__global__ __launch_bounds__(256) void scatter_kernel(const int* __restrict__ src,
                                                      const int* __restrict__ dst,
                                                      const float* __restrict__ val,
                                                      const float* __restrict__ xw,
                                                      float* out) {
    int gtid   = blockIdx.x * blockDim.x + threadIdx.x;
    int lane   = threadIdx.x & 63;
    int cg     = lane & 31;
    int half   = lane >> 5;
    int waveId = gtid >> 6;
    int nWaves = (gridDim.x * blockDim.x) >> 6;

    for (int e = waveId * 2 + half; e < N_EDGES; e += nWaves * 2) {
        int   s = src[e];
        int   d = dst[e];
        float v = val[e];
        float4 m = *(const float4*)&xw[(long long)d * OUT_CH + cg * 4];
        float* o = out + (long long)s * OUT_CH + cg * 4;
        atomicAdd(o + 0, m.x * v);
        atomicAdd(o + 1, m.y * v);
        atomicAdd(o + 2, m.z * v);
        atomicAdd(o + 3, m.w * v);
    }
}

extern "C" void kernel_launch(void* const* d_in, const int* in_sizes, int n_in,
                              void* d_out, int out_size, void* d_ws, size_t ws_size,
                              hipStream_t stream) {
    const float* x     = (const float*)d_in[0];
    const int*   esrc  = (const int*)d_in[1];
    const int*   edst  = (const int*)d_in[2];
    const float* evals = (const float*)d_in[3];
    const float* w     = (const float*)d_in[4];
    const float* bias  = (const float*)d_in[5];
    float* out = (float*)d_out;

    char* ws = (char*)d_ws;
    float* xw      = (float*)(ws + OFF_XW);
    int*   deg     = (int*)  (ws + OFF_DEG);
    int*   row_ptr = (int*)  (ws + OFF_ROWPTR);
    int*   cursor  = (int*)  (ws + OFF_CURSOR);
    int2*  packed  = (int2*) (ws + OFF_PACKED);

    // xw = x @ W  (3125 blocks x 32 rows)
    gemm_kernel<<<N_NODES / 32, 256, 0, stream>>>(x, w, xw);

    if (ws_size >= WS_REQUIRED) {
        zero_kernel<<<(N_NODES / 4 + 255) / 256, 256, 0, stream>>>(deg);
        hist_kernel<<<N_EDGES / 1024, 256, 0, stream>>>(esrc, deg);
        scan_kernel<<<1, 1024, 0, stream>>>(deg, row_ptr, cursor);
        build_kernel<<<N_EDGES / 1024, 256, 0, stream>>>(esrc, edst, evals, cursor, packed);
        aggregate_kernel<<<N_NODES / 4, 256, 0, stream>>>(row_ptr, packed, xw, bias, out);
    } else {
        init_kernel<<<(N_NODES * OUT_CH / 4) / 256, 256, 0, stream>>>(bias, out);
        scatter_kernel<<<4096, 256, 0, stream>>>(esrc, edst, evals, xw, out);
    }
}

// Round 3
// 892.027 us; speedup vs baseline: 6.7168x; 1.0936x over previous
//
#include <hip/hip_runtime.h>

// Problem constants
#define N_NODES 100000
#define N_EDGES 3200000
#define IN_CH   256
#define OUT_CH  128

// Partitioned-CSR parameters
#define NGROUP     8                       // sublists per node (≈ XCD count)
#define NS         (NGROUP * N_NODES)      // 800000 count/cursor entries
#define EPB        1024                    // edges per block (256 thr * 4)
#define NBLK_EDGE  (N_EDGES / EPB)         // 3125
#define SCAN_CHUNK 4096
#define NBLK_S1    ((NS + SCAN_CHUNK - 1) / SCAN_CHUNK)   // 196

// ---------------------------------------------------------------------------
// Workspace layout (bytes):
//   xwb    [N_NODES*OUT_CH] bf16 : 25,600,000
//   cnt    [NS]             i32  :  3,200,000
//   rp     [NS+1(+pad)]     i32  :  3,200,016
//   cursor [NS]             i32  :  3,200,000
//   bsum   [256]            i32  :      1,024
//   packed [N_EDGES]        int2 : 25,600,000
// total = 60,801,040  (R1/R2 proved ws_size >= 78 MB)
// ---------------------------------------------------------------------------
#define OFF_XWB    0
#define OFF_CNT    25600000
#define OFF_RP     28800000
#define OFF_CUR    32000016
#define OFF_BS     35200016
#define OFF_PACKED 35201040

__device__ __forceinline__ unsigned f2bf(float f) {   // fp32 -> bf16 (RNE)
    unsigned u = __float_as_uint(f);
    return (u + 0x7fffu + ((u >> 16) & 1u)) >> 16;
}

// ---------------------------------------------------------------------------
// Kernel 1: xw = x @ W (fp32 math, bf16 output). 4 rows x 4 ch per thread.
// ---------------------------------------------------------------------------
__global__ __launch_bounds__(256) void gemm_kernel(const float* __restrict__ x,
                                                   const float* __restrict__ w,
                                                   unsigned* __restrict__ xwb) {
    int tid  = threadIdx.x;
    int cg   = tid & 31;          // channels cg*4 .. cg*4+3
    int rowg = tid >> 5;          // 0..7
    int r0   = blockIdx.x * 32 + rowg * 4;

    const float4* w4  = (const float4*)w;
    const float*  xr0 = x + (long long)r0 * IN_CH;

    float4 a0 = make_float4(0.f, 0.f, 0.f, 0.f);
    float4 a1 = a0, a2 = a0, a3 = a0;

    for (int k = 0; k < IN_CH; k += 4) {
        float4 w0 = w4[(k + 0) * 32 + cg];
        float4 w1 = w4[(k + 1) * 32 + cg];
        float4 w2 = w4[(k + 2) * 32 + cg];
        float4 w3 = w4[(k + 3) * 32 + cg];
        float4 x0 = *(const float4*)&xr0[0 * IN_CH + k];
        float4 x1 = *(const float4*)&xr0[1 * IN_CH + k];
        float4 x2 = *(const float4*)&xr0[2 * IN_CH + k];
        float4 x3 = *(const float4*)&xr0[3 * IN_CH + k];

        a0.x += x0.x*w0.x + x0.y*w1.x + x0.z*w2.x + x0.w*w3.x;
        a0.y += x0.x*w0.y + x0.y*w1.y + x0.z*w2.y + x0.w*w3.y;
        a0.z += x0.x*w0.z + x0.y*w1.z + x0.z*w2.z + x0.w*w3.z;
        a0.w += x0.x*w0.w + x0.y*w1.w + x0.z*w2.w + x0.w*w3.w;

        a1.x += x1.x*w0.x + x1.y*w1.x + x1.z*w2.x + x1.w*w3.x;
        a1.y += x1.x*w0.y + x1.y*w1.y + x1.z*w2.y + x1.w*w3.y;
        a1.z += x1.x*w0.z + x1.y*w1.z + x1.z*w2.z + x1.w*w3.z;
        a1.w += x1.x*w0.w + x1.y*w1.w + x1.z*w2.w + x1.w*w3.w;

        a2.x += x2.x*w0.x + x2.y*w1.x + x2.z*w2.x + x2.w*w3.x;
        a2.y += x2.x*w0.y + x2.y*w1.y + x2.z*w2.y + x2.w*w3.y;
        a2.z += x2.x*w0.z + x2.y*w1.z + x2.z*w2.z + x2.w*w3.z;
        a2.w += x2.x*w0.w + x2.y*w1.w + x2.z*w2.w + x2.w*w3.w;

        a3.x += x3.x*w0.x + x3.y*w1.x + x3.z*w2.x + x3.w*w3.x;
        a3.y += x3.x*w0.y + x3.y*w1.y + x3.z*w2.y + x3.w*w3.y;
        a3.z += x3.x*w0.z + x3.y*w1.z + x3.z*w2.z + x3.w*w3.z;
        a3.w += x3.x*w0.w + x3.y*w1.w + x3.z*w2.w + x3.w*w3.w;
    }
    // pack 4 channels -> 2 uints (bf16x2), row stride = 64 uints
    unsigned base = (unsigned)r0 * 64 + cg * 2;
    *(uint2*)&xwb[base +   0] = make_uint2(f2bf(a0.x) | (f2bf(a0.y) << 16),
                                           f2bf(a0.z) | (f2bf(a0.w) << 16));
    *(uint2*)&xwb[base +  64] = make_uint2(f2bf(a1.x) | (f2bf(a1.y) << 16),
                                           f2bf(a1.z) | (f2bf(a1.w) << 16));
    *(uint2*)&xwb[base + 128] = make_uint2(f2bf(a2.x) | (f2bf(a2.y) << 16),
                                           f2bf(a2.z) | (f2bf(a2.w) << 16));
    *(uint2*)&xwb[base + 192] = make_uint2(f2bf(a3.x) | (f2bf(a3.y) << 16),
                                           f2bf(a3.z) | (f2bf(a3.w) << 16));
}

// ---------------------------------------------------------------------------
// CSR build, 8-way block-group partitioned
// ---------------------------------------------------------------------------
__global__ __launch_bounds__(256) void zero_kernel(int* __restrict__ cnt) {
    int i = (blockIdx.x * 256 + threadIdx.x) * 4;
    if (i < NS) *(int4*)&cnt[i] = make_int4(0, 0, 0, 0);
}

__global__ __launch_bounds__(256) void hist_kernel(const int* __restrict__ src,
                                                   int* __restrict__ cnt) {
    int g  = blockIdx.x & (NGROUP - 1);
    int e0 = blockIdx.x * EPB + threadIdx.x * 4;
    int4 s = *(const int4*)&src[e0];
    int* c = cnt + g * N_NODES;
    atomicAdd(&c[s.x], 1);
    atomicAdd(&c[s.y], 1);
    atomicAdd(&c[s.z], 1);
    atomicAdd(&c[s.w], 1);
}

// Scan phase 1: per-block sums (4096 counts / block)
__global__ __launch_bounds__(256) void scan_s1(const int* __restrict__ cnt,
                                               int* __restrict__ bsum) {
    __shared__ int wsum[4];
    int tid = threadIdx.x, lane = tid & 63, wid = tid >> 6;
    int acc = 0;
#pragma unroll
    for (int k = 0; k < 4; ++k) {
        int i0 = blockIdx.x * SCAN_CHUNK + k * 1024 + tid * 4;
        if (i0 < NS) {
            int4 v = *(const int4*)&cnt[i0];
            acc += v.x + v.y + v.z + v.w;
        }
    }
#pragma unroll
    for (int off = 32; off; off >>= 1) acc += __shfl_down(acc, off, 64);
    if (lane == 0) wsum[wid] = acc;
    __syncthreads();
    if (tid == 0) bsum[blockIdx.x] = wsum[0] + wsum[1] + wsum[2] + wsum[3];
}

// Scan phase 2: exclusive scan of block sums (NBLK_S1 = 196 <= 256)
__global__ __launch_bounds__(256) void scan_s2(int* __restrict__ bsum,
                                               int* __restrict__ rp) {
    __shared__ int wsum[4];
    int tid = threadIdx.x, lane = tid & 63, wid = tid >> 6;
    int v = (tid < NBLK_S1) ? bsum[tid] : 0;
    int s = v;
#pragma unroll
    for (int off = 1; off < 64; off <<= 1) {
        int t = __shfl_up(s, off, 64);
        if (lane >= off) s += t;
    }
    if (lane == 63) wsum[wid] = s;
    __syncthreads();
    int w0 = wsum[0], w1 = wsum[1], w2 = wsum[2], w3 = wsum[3];
    int woff = (wid > 0 ? w0 : 0) + (wid > 1 ? w1 : 0) + (wid > 2 ? w2 : 0);
    if (tid < NBLK_S1) bsum[tid] = woff + s - v;      // exclusive
    if (tid == 0) rp[NS] = w0 + w1 + w2 + w3;         // total = N_EDGES
}

// Scan phase 3: block-local exclusive scan + block offset -> rp, cursor
__global__ __launch_bounds__(256) void scan_s3(const int* __restrict__ cnt,
                                               const int* __restrict__ bsum,
                                               int* __restrict__ rp,
                                               int* __restrict__ cursor) {
    __shared__ int wsum[4];
    int tid = threadIdx.x, lane = tid & 63, wid = tid >> 6;
    int carry = bsum[blockIdx.x];
#pragma unroll
    for (int k = 0; k < 4; ++k) {
        int i0 = blockIdx.x * SCAN_CHUNK + k * 1024 + tid * 4;
        int4 v = make_int4(0, 0, 0, 0);
        if (i0 < NS) v = *(const int4*)&cnt[i0];
        int sum4 = v.x + v.y + v.z + v.w;
        int s = sum4;
#pragma unroll
        for (int off = 1; off < 64; off <<= 1) {
            int t = __shfl_up(s, off, 64);
            if (lane >= off) s += t;
        }
        if (lane == 63) wsum[wid] = s;
        __syncthreads();
        int w0 = wsum[0], w1 = wsum[1], w2 = wsum[2], w3 = wsum[3];
        int woff = (wid > 0 ? w0 : 0) + (wid > 1 ? w1 : 0) + (wid > 2 ? w2 : 0);
        int excl = carry + woff + (s - sum4);
        if (i0 < NS) {
            int4 r = make_int4(excl, excl + v.x, excl + v.x + v.y,
                               excl + v.x + v.y + v.z);
            *(int4*)&rp[i0]     = r;
            *(int4*)&cursor[i0] = r;
        }
        carry += w0 + w1 + w2 + w3;
        __syncthreads();
    }
}

__global__ __launch_bounds__(256) void build_kernel(const int* __restrict__ src,
                                                    const int* __restrict__ dst,
                                                    const float* __restrict__ val,
                                                    int* __restrict__ cursor,
                                                    int2* __restrict__ packed) {
    int g  = blockIdx.x & (NGROUP - 1);
    int e0 = blockIdx.x * EPB + threadIdx.x * 4;
    int4   s = *(const int4*)&src[e0];
    int4   d = *(const int4*)&dst[e0];
    float4 v = *(const float4*)&val[e0];
    int* cur = cursor + g * N_NODES;
    int p;
    p = atomicAdd(&cur[s.x], 1); packed[p] = make_int2(d.x, __float_as_int(v.x));
    p = atomicAdd(&cur[s.y], 1); packed[p] = make_int2(d.y, __float_as_int(v.y));
    p = atomicAdd(&cur[s.z], 1); packed[p] = make_int2(d.z, __float_as_int(v.z));
    p = atomicAdd(&cur[s.w], 1); packed[p] = make_int2(d.w, __float_as_int(v.w));
}

// ---------------------------------------------------------------------------
// Aggregate: one node per wave; 64 lanes x 2 channels (bf16x2 gathers,
// fp32 accumulate); walks the node's 8 group-sublists; bias fused.
// ---------------------------------------------------------------------------
__global__ __launch_bounds__(256) void aggregate_kernel(const int* __restrict__ rp,
                                                        const int2* __restrict__ packed,
                                                        const unsigned* __restrict__ xwb,
                                                        const float* __restrict__ bias,
                                                        float* __restrict__ out) {
    int node = blockIdx.x * 4 + (threadIdx.x >> 6);
    int lane = threadIdx.x & 63;
    float2 acc = *(const float2*)&bias[lane * 2];

    for (int g = 0; g < NGROUP; ++g) {
        int i   = g * N_NODES + node;
        int e   = rp[i];
        int end = rp[i + 1];
        for (; e + 4 <= end; e += 4) {
            int2 p0 = packed[e + 0];
            int2 p1 = packed[e + 1];
            int2 p2 = packed[e + 2];
            int2 p3 = packed[e + 3];
            unsigned u0 = xwb[p0.x * 64 + lane];
            unsigned u1 = xwb[p1.x * 64 + lane];
            unsigned u2 = xwb[p2.x * 64 + lane];
            unsigned u3 = xwb[p3.x * 64 + lane];
            float v0 = __int_as_float(p0.y), v1 = __int_as_float(p1.y);
            float v2 = __int_as_float(p2.y), v3 = __int_as_float(p3.y);
            acc.x += v0 * __uint_as_float(u0 << 16);
            acc.y += v0 * __uint_as_float(u0 & 0xffff0000u);
            acc.x += v1 * __uint_as_float(u1 << 16);
            acc.y += v1 * __uint_as_float(u1 & 0xffff0000u);
            acc.x += v2 * __uint_as_float(u2 << 16);
            acc.y += v2 * __uint_as_float(u2 & 0xffff0000u);
            acc.x += v3 * __uint_as_float(u3 << 16);
            acc.y += v3 * __uint_as_float(u3 & 0xffff0000u);
        }
        for (; e < end; ++e) {
            int2 p = packed[e];
            unsigned u = xwb[p.x * 64 + lane];
            float v = __int_as_float(p.y);
            acc.x += v * __uint_as_float(u << 16);
            acc.y += v * __uint_as_float(u & 0xffff0000u);
        }
    }
    *(float2*)&out[(long long)node * OUT_CH + lane * 2] = acc;
}

extern "C" void kernel_launch(void* const* d_in, const int* in_sizes, int n_in,
                              void* d_out, int out_size, void* d_ws, size_t ws_size,
                              hipStream_t stream) {
    const float* x     = (const float*)d_in[0];
    const int*   esrc  = (const int*)d_in[1];
    const int*   edst  = (const int*)d_in[2];
    const float* evals = (const float*)d_in[3];
    const float* w     = (const float*)d_in[4];
    const float* bias  = (const float*)d_in[5];
    float* out = (float*)d_out;

    char* ws = (char*)d_ws;
    unsigned* xwb    = (unsigned*)(ws + OFF_XWB);
    int*      cnt    = (int*)     (ws + OFF_CNT);
    int*      rp     = (int*)     (ws + OFF_RP);
    int*      cursor = (int*)     (ws + OFF_CUR);
    int*      bsum   = (int*)     (ws + OFF_BS);
    int2*     packed = (int2*)    (ws + OFF_PACKED);

    gemm_kernel<<<N_NODES / 32, 256, 0, stream>>>(x, w, xwb);
    zero_kernel<<<(NS / 4 + 255) / 256, 256, 0, stream>>>(cnt);
    hist_kernel<<<NBLK_EDGE, 256, 0, stream>>>(esrc, cnt);
    scan_s1<<<NBLK_S1, 256, 0, stream>>>(cnt, bsum);
    scan_s2<<<1, 256, 0, stream>>>(bsum, rp);
    scan_s3<<<NBLK_S1, 256, 0, stream>>>(cnt, bsum, rp, cursor);
    build_kernel<<<NBLK_EDGE, 256, 0, stream>>>(esrc, edst, evals, cursor, packed);
    aggregate_kernel<<<N_NODES / 4, 256, 0, stream>>>(rp, packed, xwb, bias, out);
}

// Round 4
// 768.483 us; speedup vs baseline: 7.7967x; 1.1608x over previous
//
#include <hip/hip_runtime.h>

// Problem constants
#define N_NODES 100000
#define N_EDGES 3200000
#define IN_CH   256
#define OUT_CH  128

// Partitioned-CSR parameters
#define NGROUP     8                       // sublists per node (≈ XCD count)
#define NS         (NGROUP * N_NODES)      // 800000 count/cursor entries
#define EPB        1024                    // edges per block (256 thr * 4)
#define NBLK_EDGE  (N_EDGES / EPB)         // 3125
#define SCAN_CHUNK 4096
#define NBLK_S1    ((NS + SCAN_CHUNK - 1) / SCAN_CHUNK)   // 196

// ---------------------------------------------------------------------------
// Workspace layout (bytes):
//   xwb    [N_NODES*OUT_CH] bf16 : 25,600,000
//   wbf    [128][256]       bf16 :     65,536   (W^T, n-major)
//   cnt    [NS]             i32  :  3,200,000
//   rp     [NS+1(+pad)]     i32  :  3,200,016
//   cursor [NS]             i32  :  3,200,000
//   bsum   [256]            i32  :      1,024
//   packed [N_EDGES]        int2 : 25,600,000
// total = 60,866,576  (ws_size >= 78,000,016 proven in R2)
// ---------------------------------------------------------------------------
#define OFF_XWB    0
#define OFF_WBF    25600000
#define OFF_CNT    25665536
#define OFF_RP     28865536
#define OFF_CUR    32065552
#define OFF_BS     35265552
#define OFF_PACKED 35266576

typedef __attribute__((ext_vector_type(8))) short    bf8;   // 8 bf16 = 4 VGPRs
typedef __attribute__((ext_vector_type(4))) float    f4;    // C/D frag
typedef __attribute__((ext_vector_type(4))) unsigned uv4;   // 16B load vehicle

__device__ __forceinline__ unsigned f2bf(float f) {   // fp32 -> bf16 (RNE)
    unsigned u = __float_as_uint(f);
    return (u + 0x7fffu + ((u >> 16) & 1u)) >> 16;
}

// ---------------------------------------------------------------------------
// W^T conversion: w[256][128] fp32 -> wbf[128][256] bf16 (n-major).
// 128 blocks x 256 thr; coalesced reads, one-time 2B scattered writes.
// ---------------------------------------------------------------------------
__global__ __launch_bounds__(256) void wcvt_kernel(const float* __restrict__ w,
                                                   unsigned short* __restrict__ wbf) {
    int t = threadIdx.x;
    int k = blockIdx.x * 2 + (t >> 7);
    int n = t & 127;
    wbf[n * 256 + k] = (unsigned short)f2bf(w[k * 128 + n]);
}

// ---------------------------------------------------------------------------
// MFMA GEMM: xw = x @ W (bf16 inputs, fp32 accumulate, bf16 output).
// Wave tile = 16 rows x 128 cols (8 col-tiles of mfma_f32_16x16x32_bf16).
// Block = 4 waves = 64 rows. Memory-bound: streams x once, B from L1/L2.
// A-frag: A[m=lane&15][k=q*8+j]; B-frag: B[k=q*8+j][n=lane&15];
// C/D:    D[row=q*4+reg][col=lane&15]   (verified maps, learn_hip m89/m120)
// ---------------------------------------------------------------------------
__global__ __launch_bounds__(256) void gemm_kernel(const float* __restrict__ x,
                                                   const unsigned short* __restrict__ wbf,
                                                   unsigned* __restrict__ xwb) {
    int wave = threadIdx.x >> 6;
    int lane = threadIdx.x & 63;
    int m = lane & 15;
    int q = lane >> 4;
    int r0 = blockIdx.x * 64 + wave * 16;

    int arow = r0 + m;
    if (arow >= N_NODES) arow = N_NODES - 1;     // clamp loads; stores guarded
    const float* xr = x + (long long)arow * IN_CH + q * 8;

    f4 acc[8];
#pragma unroll
    for (int ct = 0; ct < 8; ++ct) acc[ct] = (f4){0.f, 0.f, 0.f, 0.f};

#pragma unroll
    for (int ks = 0; ks < 8; ++ks) {             // k0 = ks*32
        float4 xa = *(const float4*)(xr + ks * 32);
        float4 xb = *(const float4*)(xr + ks * 32 + 4);
        bf8 a;
        a[0] = (short)f2bf(xa.x); a[1] = (short)f2bf(xa.y);
        a[2] = (short)f2bf(xa.z); a[3] = (short)f2bf(xa.w);
        a[4] = (short)f2bf(xb.x); a[5] = (short)f2bf(xb.y);
        a[6] = (short)f2bf(xb.z); a[7] = (short)f2bf(xb.w);
#pragma unroll
        for (int ct = 0; ct < 8; ++ct) {
            uv4 u = *(const uv4*)&wbf[(ct * 16 + m) * 256 + ks * 32 + q * 8];
            bf8 b = __builtin_bit_cast(bf8, u);
            acc[ct] = __builtin_amdgcn_mfma_f32_16x16x32_bf16(a, b, acc[ct], 0, 0, 0);
        }
    }

    // Epilogue: pack col pairs (m, m^1) into bf16x2 words; xwb layout is
    // identical to R3 (row stride 64 uints, low half = even channel).
#pragma unroll
    for (int ct = 0; ct < 8; ++ct) {
#pragma unroll
        for (int r = 0; r < 4; ++r) {
            float v = acc[ct][r];
            float p = __shfl_xor(v, 1, 64);
            unsigned mine = f2bf(v), oth = f2bf(p);
            if (!(m & 1)) {
                int row = r0 + q * 4 + r;
                if (row < N_NODES)
                    xwb[row * 64 + ct * 8 + (m >> 1)] = mine | (oth << 16);
            }
        }
    }
}

// ---------------------------------------------------------------------------
// CSR build, 8-way block-group partitioned (unchanged from R3)
// ---------------------------------------------------------------------------
__global__ __launch_bounds__(256) void zero_kernel(int* __restrict__ cnt) {
    int i = (blockIdx.x * 256 + threadIdx.x) * 4;
    if (i < NS) *(int4*)&cnt[i] = make_int4(0, 0, 0, 0);
}

__global__ __launch_bounds__(256) void hist_kernel(const int* __restrict__ src,
                                                   int* __restrict__ cnt) {
    int g  = blockIdx.x & (NGROUP - 1);
    int e0 = blockIdx.x * EPB + threadIdx.x * 4;
    int4 s = *(const int4*)&src[e0];
    int* c = cnt + g * N_NODES;
    atomicAdd(&c[s.x], 1);
    atomicAdd(&c[s.y], 1);
    atomicAdd(&c[s.z], 1);
    atomicAdd(&c[s.w], 1);
}

__global__ __launch_bounds__(256) void scan_s1(const int* __restrict__ cnt,
                                               int* __restrict__ bsum) {
    __shared__ int wsum[4];
    int tid = threadIdx.x, lane = tid & 63, wid = tid >> 6;
    int acc = 0;
#pragma unroll
    for (int k = 0; k < 4; ++k) {
        int i0 = blockIdx.x * SCAN_CHUNK + k * 1024 + tid * 4;
        if (i0 < NS) {
            int4 v = *(const int4*)&cnt[i0];
            acc += v.x + v.y + v.z + v.w;
        }
    }
#pragma unroll
    for (int off = 32; off; off >>= 1) acc += __shfl_down(acc, off, 64);
    if (lane == 0) wsum[wid] = acc;
    __syncthreads();
    if (tid == 0) bsum[blockIdx.x] = wsum[0] + wsum[1] + wsum[2] + wsum[3];
}

__global__ __launch_bounds__(256) void scan_s2(int* __restrict__ bsum,
                                               int* __restrict__ rp) {
    __shared__ int wsum[4];
    int tid = threadIdx.x, lane = tid & 63, wid = tid >> 6;
    int v = (tid < NBLK_S1) ? bsum[tid] : 0;
    int s = v;
#pragma unroll
    for (int off = 1; off < 64; off <<= 1) {
        int t = __shfl_up(s, off, 64);
        if (lane >= off) s += t;
    }
    if (lane == 63) wsum[wid] = s;
    __syncthreads();
    int w0 = wsum[0], w1 = wsum[1], w2 = wsum[2], w3 = wsum[3];
    int woff = (wid > 0 ? w0 : 0) + (wid > 1 ? w1 : 0) + (wid > 2 ? w2 : 0);
    if (tid < NBLK_S1) bsum[tid] = woff + s - v;
    if (tid == 0) rp[NS] = w0 + w1 + w2 + w3;
}

__global__ __launch_bounds__(256) void scan_s3(const int* __restrict__ cnt,
                                               const int* __restrict__ bsum,
                                               int* __restrict__ rp,
                                               int* __restrict__ cursor) {
    __shared__ int wsum[4];
    int tid = threadIdx.x, lane = tid & 63, wid = tid >> 6;
    int carry = bsum[blockIdx.x];
#pragma unroll
    for (int k = 0; k < 4; ++k) {
        int i0 = blockIdx.x * SCAN_CHUNK + k * 1024 + tid * 4;
        int4 v = make_int4(0, 0, 0, 0);
        if (i0 < NS) v = *(const int4*)&cnt[i0];
        int sum4 = v.x + v.y + v.z + v.w;
        int s = sum4;
#pragma unroll
        for (int off = 1; off < 64; off <<= 1) {
            int t = __shfl_up(s, off, 64);
            if (lane >= off) s += t;
        }
        if (lane == 63) wsum[wid] = s;
        __syncthreads();
        int w0 = wsum[0], w1 = wsum[1], w2 = wsum[2], w3 = wsum[3];
        int woff = (wid > 0 ? w0 : 0) + (wid > 1 ? w1 : 0) + (wid > 2 ? w2 : 0);
        int excl = carry + woff + (s - sum4);
        if (i0 < NS) {
            int4 r = make_int4(excl, excl + v.x, excl + v.x + v.y,
                               excl + v.x + v.y + v.z);
            *(int4*)&rp[i0]     = r;
            *(int4*)&cursor[i0] = r;
        }
        carry += w0 + w1 + w2 + w3;
        __syncthreads();
    }
}

__global__ __launch_bounds__(256) void build_kernel(const int* __restrict__ src,
                                                    const int* __restrict__ dst,
                                                    const float* __restrict__ val,
                                                    int* __restrict__ cursor,
                                                    int2* __restrict__ packed) {
    int g  = blockIdx.x & (NGROUP - 1);
    int e0 = blockIdx.x * EPB + threadIdx.x * 4;
    int4   s = *(const int4*)&src[e0];
    int4   d = *(const int4*)&dst[e0];
    float4 v = *(const float4*)&val[e0];
    int* cur = cursor + g * N_NODES;
    int p;
    p = atomicAdd(&cur[s.x], 1); packed[p] = make_int2(d.x, __float_as_int(v.x));
    p = atomicAdd(&cur[s.y], 1); packed[p] = make_int2(d.y, __float_as_int(v.y));
    p = atomicAdd(&cur[s.z], 1); packed[p] = make_int2(d.z, __float_as_int(v.z));
    p = atomicAdd(&cur[s.w], 1); packed[p] = make_int2(d.w, __float_as_int(v.w));
}

// ---------------------------------------------------------------------------
// Aggregate: one node per wave; bf16x2 gathers, fp32 accumulate (unchanged)
// ---------------------------------------------------------------------------
__global__ __launch_bounds__(256) void aggregate_kernel(const int* __restrict__ rp,
                                                        const int2* __restrict__ packed,
                                                        const unsigned* __restrict__ xwb,
                                                        const float* __restrict__ bias,
                                                        float* __restrict__ out) {
    int node = blockIdx.x * 4 + (threadIdx.x >> 6);
    int lane = threadIdx.x & 63;
    float2 acc = *(const float2*)&bias[lane * 2];

    for (int g = 0; g < NGROUP; ++g) {
        int i   = g * N_NODES + node;
        int e   = rp[i];
        int end = rp[i + 1];
        for (; e + 4 <= end; e += 4) {
            int2 p0 = packed[e + 0];
            int2 p1 = packed[e + 1];
            int2 p2 = packed[e + 2];
            int2 p3 = packed[e + 3];
            unsigned u0 = xwb[p0.x * 64 + lane];
            unsigned u1 = xwb[p1.x * 64 + lane];
            unsigned u2 = xwb[p2.x * 64 + lane];
            unsigned u3 = xwb[p3.x * 64 + lane];
            float v0 = __int_as_float(p0.y), v1 = __int_as_float(p1.y);
            float v2 = __int_as_float(p2.y), v3 = __int_as_float(p3.y);
            acc.x += v0 * __uint_as_float(u0 << 16);
            acc.y += v0 * __uint_as_float(u0 & 0xffff0000u);
            acc.x += v1 * __uint_as_float(u1 << 16);
            acc.y += v1 * __uint_as_float(u1 & 0xffff0000u);
            acc.x += v2 * __uint_as_float(u2 << 16);
            acc.y += v2 * __uint_as_float(u2 & 0xffff0000u);
            acc.x += v3 * __uint_as_float(u3 << 16);
            acc.y += v3 * __uint_as_float(u3 & 0xffff0000u);
        }
        for (; e < end; ++e) {
            int2 p = packed[e];
            unsigned u = xwb[p.x * 64 + lane];
            float v = __int_as_float(p.y);
            acc.x += v * __uint_as_float(u << 16);
            acc.y += v * __uint_as_float(u & 0xffff0000u);
        }
    }
    *(float2*)&out[(long long)node * OUT_CH + lane * 2] = acc;
}

extern "C" void kernel_launch(void* const* d_in, const int* in_sizes, int n_in,
                              void* d_out, int out_size, void* d_ws, size_t ws_size,
                              hipStream_t stream) {
    const float* x     = (const float*)d_in[0];
    const int*   esrc  = (const int*)d_in[1];
    const int*   edst  = (const int*)d_in[2];
    const float* evals = (const float*)d_in[3];
    const float* w     = (const float*)d_in[4];
    const float* bias  = (const float*)d_in[5];
    float* out = (float*)d_out;

    char* ws = (char*)d_ws;
    unsigned*       xwb    = (unsigned*)      (ws + OFF_XWB);
    unsigned short* wbf    = (unsigned short*)(ws + OFF_WBF);
    int*            cnt    = (int*)           (ws + OFF_CNT);
    int*            rp     = (int*)           (ws + OFF_RP);
    int*            cursor = (int*)           (ws + OFF_CUR);
    int*            bsum   = (int*)           (ws + OFF_BS);
    int2*           packed = (int2*)          (ws + OFF_PACKED);

    wcvt_kernel<<<128, 256, 0, stream>>>(w, wbf);
    gemm_kernel<<<(N_NODES + 63) / 64, 256, 0, stream>>>(x, wbf, xwb);
    zero_kernel<<<(NS / 4 + 255) / 256, 256, 0, stream>>>(cnt);
    hist_kernel<<<NBLK_EDGE, 256, 0, stream>>>(esrc, cnt);
    scan_s1<<<NBLK_S1, 256, 0, stream>>>(cnt, bsum);
    scan_s2<<<1, 256, 0, stream>>>(bsum, rp);
    scan_s3<<<NBLK_S1, 256, 0, stream>>>(cnt, bsum, rp, cursor);
    build_kernel<<<NBLK_EDGE, 256, 0, stream>>>(esrc, edst, evals, cursor, packed);
    aggregate_kernel<<<N_NODES / 4, 256, 0, stream>>>(rp, packed, xwb, bias, out);
}